// Round 5
// baseline (137.221 us; speedup 1.0000x reference)
//
#include <hip/hip_runtime.h>
#include <math.h>

#define NROW 8192
#define DDIM 128
#define DP 32          // prescan dims (exact lower bound of full distance)
#define CAP 16384
#define NITERS 100
#define NWARM 6
#define AC (1.0f / 8192.0f)

struct Entry { int i, j; float s, t; };

// ws layout (bytes), no overlays:
// 0        x2   float[NROW]
// 32768    y2   float[NROW]
// 65536    x2p  float[NROW]   partial norms (dims 0..31)
// 98304    y2p  float[NROW]
// 131072   counts int[8]      [0..2]=list counts, [6]=epi done-counter
// 131136   accum double[3][264]
// 137472   lists Entry[3][CAP]      -> 923904
// 923904   Xbf ushort[NROW*DP]      -> 1448192
// 1448192  Ybf ushort[NROW*DP]      -> 1972480
// 1972480  sdiag float[3*NROW]      -> 2070784
// 2070784  tdiag float[3*NROW]      -> 2169088
// 2169088  u_g  float[3*NROW]       -> 2267392
// 2267392  v_g  float[3*NROW]       -> 2365696

typedef __attribute__((ext_vector_type(8))) short frag_ab;   // 8 bf16
typedef __attribute__((ext_vector_type(4))) float frag_cd;   // 4 fp32

__device__ inline unsigned short f2bf(float f) {
    unsigned u = __float_as_uint(f);
    return (unsigned short)((u + 0x7FFFu + ((u >> 16) & 1u)) >> 16);  // RN-even
}

// shared arithmetic helpers (identical text everywhere -> identical rounding)
__device__ inline float wave_dot128(const float* __restrict__ ar, const float* __restrict__ br, int lane) {
    float dot = ar[lane] * br[lane] + ar[lane + 64] * br[lane + 64];
    for (int o = 32; o; o >>= 1) dot += __shfl_down(dot, o, 64);
    return dot;
}
__device__ inline void st_from_raw(float raw, float& s, float& tv) {
    float C = fmaxf(raw, 0.0f);
    float sc = fmaxf(-C * 100.0f, -50.0f);
    float K = fmaxf(expf(sc), 1e-8f);
    s = K - 1e-8f;
    tv = (raw >= 0.f) ? s * C : (-1e-8f) * raw;   // exactly 0 when s==0
}
__device__ inline double ald(const double* p) {
    return __hip_atomic_load(p, __ATOMIC_RELAXED, __HIP_MEMORY_SCOPE_AGENT);
}

// One wave per row r: norms + partial norms + bf16(dims 0..31) for BOTH X_r and
// Y_r, plus all three diagonal s,t (p=0,1,2). init folded in. Reads each input
// row once cold (re-reads hit L1).
__global__ void norms_k(const float* __restrict__ X, const float* __restrict__ Y,
                        float* __restrict__ x2, float* __restrict__ y2,
                        float* __restrict__ x2p, float* __restrict__ y2p,
                        unsigned short* __restrict__ Xbf, unsigned short* __restrict__ Ybf,
                        int* counts, double* accum, Entry* lists,
                        float* __restrict__ sdiag, float* __restrict__ tdiag) {
    int idx = blockIdx.x * 256 + threadIdx.x;
    if (idx < 8) counts[idx] = (idx < 3) ? NROW : 0;
    if (idx < 3 * 264) accum[idx] = 0.0;
    int r = idx >> 6;
    int lane = idx & 63;
    if (r >= NROW) return;
    const float* xr = X + (size_t)r * DDIM;
    const float* yr = Y + (size_t)r * DDIM;
    float2 xv = *(const float2*)(xr + lane * 2);
    float2 yv = *(const float2*)(yr + lane * 2);
    if (lane < 16) {
        unsigned pkx = (unsigned)f2bf(xv.x) | ((unsigned)f2bf(xv.y) << 16);
        unsigned pky = (unsigned)f2bf(yv.x) | ((unsigned)f2bf(yv.y) << 16);
        *(unsigned*)(Xbf + (size_t)r * DP + lane * 2) = pkx;
        *(unsigned*)(Ybf + (size_t)r * DP + lane * 2) = pky;
    }
    float s = xv.x * xv.x + xv.y * xv.y;           // X norm (float2 pattern)
    float sy = yv.x * yv.x + yv.y * yv.y;          // Y norm (float2 pattern)
    float sp = (lane < 16) ? s : 0.f;
    float spy = (lane < 16) ? sy : 0.f;
    for (int o = 32; o; o >>= 1) s += __shfl_down(s, o, 64);
    for (int o = 32; o; o >>= 1) sy += __shfl_down(sy, o, 64);
    for (int o = 8; o; o >>= 1) sp += __shfl_down(sp, o, 64);
    for (int o = 8; o; o >>= 1) spy += __shfl_down(spy, o, 64);
    // dots in exact layout (matches exact-path reduce order)
    float dxx = wave_dot128(xr, xr, lane);
    float dyy = wave_dot128(yr, yr, lane);
    float dxy = wave_dot128(xr, yr, lane);
    if (lane == 0) {
        x2[r] = s; x2p[r] = sp;
        y2[r] = sy; y2p[r] = spy;
        float s1, t1; st_from_raw(s + s - 2.0f * dxx, s1, t1);        // p=1 (X,X)
        sdiag[NROW + r] = s1; tdiag[NROW + r] = t1;
        Entry e1; e1.i = r; e1.j = r; e1.s = s1; e1.t = t1;
        lists[(size_t)CAP + r] = e1;
        float s0, t0; st_from_raw(s + sy - 2.0f * dxy, s0, t0);       // p=0 (X,Y)
        sdiag[r] = s0; tdiag[r] = t0;
        Entry e0; e0.i = r; e0.j = r; e0.s = s0; e0.t = t0;
        lists[r] = e0;
        float s2, t2; st_from_raw(sy + sy - 2.0f * dyy, s2, t2);      // p=2 (Y,Y)
        sdiag[2 * NROW + r] = s2; tdiag[2 * NROW + r] = t2;
        Entry e2; e2.i = r; e2.j = r; e2.s = s2; e2.t = t2;
        lists[(size_t)2 * CAP + r] = e2;
    }
}

// MFMA prescan over dims 0..31, 256x128 tiles, 512 threads (8 waves of 64x64).
// LDS-free: fragments and norms loaded straight from global (entire bf16 set is
// 1 MB = L2-resident; K=32 means zero LDS reuse, so staging was pure overhead).
// Same bits -> same MFMA output -> identical listed set.
// Group filter: per 16-elem group, min(na,4rows)+min(yj,4cols)-2*max(acc,16) < 2
// escalates to the per-element test (monotone fp => identical listed set).
__global__ __launch_bounds__(512) void scan_k(const unsigned short* __restrict__ Xbf,
                                              const unsigned short* __restrict__ Ybf,
                                              const float* __restrict__ x2p,
                                              const float* __restrict__ y2p,
                                              int* counts, Entry* lists) {
    // flat decode: p0 = 32x64 tiles; p1/p2 upper wedge by >= 2bx (1056 each)
    int bid = blockIdx.x;
    int p, bx, by;
    if (bid < 2048) { p = 0; bx = bid >> 6; by = bid & 63; }
    else {
        int r = bid - 2048;
        p = 1 + (r >= 1056);
        int q = r - (p == 2) * 1056;
        int a = (int)((65.0f - sqrtf((float)(4225 - 4 * q))) * 0.5f);
        while (65 * a - a * a > q) a--;
        while (65 * (a + 1) - (a + 1) * (a + 1) <= q) a++;
        bx = a;
        by = 2 * a + (q - (65 * a - a * a));
    }
    const unsigned short* Ab = (p == 2) ? Ybf : Xbf;
    const unsigned short* Bb = (p == 0) ? Ybf : ((p == 1) ? Xbf : Ybf);
    const float* na = (p == 2) ? y2p : x2p;
    const float* nb = (p == 0) ? y2p : ((p == 1) ? x2p : y2p);
    int i0 = bx * 256, j0 = by * 128;

    int t = threadIdx.x;
    int w = t >> 6, lane = t & 63;
    int lm = lane & 15, quad = lane >> 4;
    int wr = (w >> 1) * 64, wc = (w & 1) * 64;

    const unsigned short* ga = Ab + (size_t)i0 * DP;
    const unsigned short* gb = Bb + (size_t)j0 * DP;
    frag_ab a[4], b[4];
    #pragma unroll
    for (int rt = 0; rt < 4; rt++)
        a[rt] = *(const frag_ab*)(ga + (size_t)(wr + rt * 16 + lm) * DP + quad * 8);
    #pragma unroll
    for (int ct = 0; ct < 4; ct++)
        b[ct] = *(const frag_ab*)(gb + (size_t)(wc + ct * 16 + lm) * DP + quad * 8);

    frag_cd acc[4][4];
    #pragma unroll
    for (int rt = 0; rt < 4; rt++)
        #pragma unroll
        for (int ct = 0; ct < 4; ct++) acc[rt][ct] = (frag_cd){0.f, 0.f, 0.f, 0.f};
    #pragma unroll
    for (int rt = 0; rt < 4; rt++)
        #pragma unroll
        for (int ct = 0; ct < 4; ct++)
            acc[rt][ct] = __builtin_amdgcn_mfma_f32_16x16x32_bf16(a[rt], b[ct], acc[rt][ct], 0, 0, 0);

    Entry* list = lists + (size_t)p * CAP;
    float yj_[4];
    #pragma unroll
    for (int ct = 0; ct < 4; ct++) yj_[ct] = nb[j0 + wc + ct * 16 + lm];
    float minyj = fminf(fminf(yj_[0], yj_[1]), fminf(yj_[2], yj_[3]));

    #pragma unroll
    for (int rt = 0; rt < 4; rt++) {
        // this lane's 4-row norm quad (16B aligned, broadcast across lm group)
        float nv[4];
        #pragma unroll
        for (int reg = 0; reg < 4; reg++) nv[reg] = na[i0 + wr + rt * 16 + quad * 4 + reg];
        float m0 = fmaxf(fmaxf(acc[rt][0][0], acc[rt][0][1]), fmaxf(acc[rt][0][2], acc[rt][0][3]));
        float m1 = fmaxf(fmaxf(acc[rt][1][0], acc[rt][1][1]), fmaxf(acc[rt][1][2], acc[rt][1][3]));
        float m2 = fmaxf(fmaxf(acc[rt][2][0], acc[rt][2][1]), fmaxf(acc[rt][2][2], acc[rt][2][3]));
        float m3 = fmaxf(fmaxf(acc[rt][3][0], acc[rt][3][1]), fmaxf(acc[rt][3][2], acc[rt][3][3]));
        float mx = fmaxf(fmaxf(m0, m1), fmaxf(m2, m3));
        float mna = fminf(fminf(nv[0], nv[1]), fminf(nv[2], nv[3]));
        if (mna + minyj - 2.f * mx < 2.0f) {
            #pragma unroll
            for (int ct = 0; ct < 4; ct++) {
                int j = j0 + wc + ct * 16 + lm;
                float yj = yj_[ct];
                #pragma unroll
                for (int reg = 0; reg < 4; reg++) {
                    int i = i0 + wr + rt * 16 + quad * 4 + reg;
                    float Ct = nv[reg] + yj - 2.f * acc[rt][ct][reg];
                    if (Ct < 2.0f && i != j) {
                        if (p == 0) {
                            int idx = atomicAdd(&counts[0], 1);
                            if (idx < CAP) { Entry e; e.i = i; e.j = j; e.s = 0.f; e.t = 0.f; list[idx] = e; }
                        } else if (i < j) {
                            int idx = atomicAdd(&counts[p], 2);
                            if (idx < CAP) { Entry e; e.i = i; e.j = j; e.s = 0.f; e.t = 0.f; list[idx] = e; }
                            if (idx + 1 < CAP) { Entry e; e.i = j; e.j = i; e.s = 0.f; e.t = 0.f; list[idx + 1] = e; }
                        }
                    }
                }
            }
        }
    }
}

// sink2: (1) folded exact pass for off-diag listed entries (usually empty),
// (2) warm Sinkhorn + freeze, or full fallback when off-diag active entries exist.
__global__ __launch_bounds__(1024, 1) void sink2_k(const int* counts,
                                                   Entry* lists,
                                                   const float* __restrict__ sdiag,
                                                   float* __restrict__ u_g,
                                                   float* __restrict__ v_g,
                                                   double* accum,
                                                   const float* __restrict__ X,
                                                   const float* __restrict__ Y,
                                                   const float* __restrict__ x2,
                                                   const float* __restrict__ y2) {
    int p = blockIdx.x;
    Entry* listm = lists + (size_t)p * CAP;
    const Entry* list = listm;
    int cnt = counts[p]; if (cnt > CAP) cnt = CAP;
    double* acc = accum + (size_t)p * 264;
    float* up = u_g + (size_t)p * NROW;
    float* vp = v_g + (size_t)p * NROW;

    __shared__ float u_s[NROW];   // fallback only
    __shared__ float v_s[NROW];
    __shared__ float redS[2][16];
    __shared__ unsigned redC[16];
    __shared__ int nres_s;
    int t = threadIdx.x;
    int wid = t >> 6, lane = t & 63;

    // ---- folded exact: off-diagonal entries [NROW, cnt) ----
    if (t == 0) nres_s = 0;
    __syncthreads();
    {
        const float* A = (p == 2) ? Y : X;
        const float* B = (p == 0) ? Y : ((p == 1) ? X : Y);
        const float* na = (p == 2) ? y2 : x2;
        const float* nb = (p == 0) ? y2 : ((p == 1) ? x2 : y2);
        int act = 0;
        for (int e = NROW + wid; e < cnt; e += 16) {
            int i = listm[e].i, j = listm[e].j;
            float dot = wave_dot128(A + (size_t)i * DDIM, B + (size_t)j * DDIM, lane);
            if (lane == 0) {
                float raw = na[i] + nb[j] - 2.0f * dot;
                float s, tv; st_from_raw(raw, s, tv);
                listm[e].s = s; listm[e].t = tv;
                if (s != 0.f || tv != 0.f) act++;
            }
        }
        if (lane == 0 && act) atomicAdd(&nres_s, act);
    }
    __syncthreads();
    int nres = nres_s;

    if (nres == 0) {
        float vk[8], uk[8], sk[8];
        unsigned pv2[8];
        #pragma unroll
        for (int k = 0; k < 8; k++) {
            sk[k] = sdiag[p * NROW + t + 1024 * k];
            vk[k] = 1.0f; uk[k] = AC; pv2[k] = 0xFFFFFFFFu;
        }
        unsigned flags = 3u;
        int par = 0, last = 0, done = 0;
        float bu_last = 0.f;
        for (int it = 0; it < NWARM; it++) {
            float s = 0.f;
            #pragma unroll
            for (int k = 0; k < 8; k++) s += vk[k];
            for (int o = 32; o; o >>= 1) s += __shfl_down(s, o, 64);
            if (lane == 0) { redS[par][wid] = s; redC[wid] = flags; }
            __syncthreads();
            float sumv = 0.f; unsigned anyf = 0;
            #pragma unroll
            for (int w2 = 0; w2 < 16; w2++) { sumv += redS[par][w2]; anyf |= redC[w2]; }
            par ^= 1;
            if (it > 0) {
                if (!(anyf & 1)) { done = 1; break; }
                if (!(anyf & 2)) {
                    if (((NITERS - it) & 1) == 0) { done = 1; break; }
                    last = 1;
                }
            }
            float base = 1e-8f * sumv;
            #pragma unroll
            for (int k = 0; k < 8; k++) {
                float kv = fmaxf(base + sk[k] * vk[k], 1e-8f);
                uk[k] = AC * __builtin_amdgcn_rcpf(kv);
            }
            s = 0.f;
            #pragma unroll
            for (int k = 0; k < 8; k++) s += uk[k];
            for (int o = 32; o; o >>= 1) s += __shfl_down(s, o, 64);
            if (lane == 0) redS[par][wid] = s;
            __syncthreads();
            float sumu = 0.f;
            #pragma unroll
            for (int w2 = 0; w2 < 16; w2++) sumu += redS[par][w2];
            par ^= 1;
            base = 1e-8f * sumu;
            bu_last = base;
            unsigned d1 = 0, d2 = 0;
            #pragma unroll
            for (int k = 0; k < 8; k++) {
                float kv = fmaxf(base + sk[k] * uk[k], 1e-8f);
                float nv = AC * __builtin_amdgcn_rcpf(kv);
                unsigned nb_ = __float_as_uint(nv);
                d1 |= nb_ ^ __float_as_uint(vk[k]);
                d2 |= nb_ ^ pv2[k];
                pv2[k] = __float_as_uint(vk[k]);
                vk[k] = nv;
            }
            flags = (__any(d1 != 0) ? 1u : 0u) | (__any(d2 != 0) ? 2u : 0u);
            if (last) { done = 1; break; }
        }
        float bv_f = 0.f;
        int R = 0;
        if (!done) {
            float s = 0.f;
            #pragma unroll
            for (int k = 0; k < 8; k++) s += vk[k];
            for (int o = 32; o; o >>= 1) s += __shfl_down(s, o, 64);
            if (lane == 0) redS[par][wid] = s;
            __syncthreads();
            float sumv = 0.f;
            #pragma unroll
            for (int w2 = 0; w2 < 16; w2++) sumv += redS[par][w2];
            bv_f = 1e-8f * sumv;
            R = NITERS - NWARM;
        }
        #pragma unroll
        for (int k = 0; k < 8; k++) {
            int i = t + 1024 * k;
            up[i] = uk[k]; vp[i] = vk[k];
        }
        if (t == 0) { acc[5] = (double)R; acc[6] = (double)bu_last; acc[7] = (double)bv_f; }
    } else {
        // -------- fallback: general sparse scatter, full 100 iterations --------
        for (int i = t; i < NROW; i += 1024) { u_s[i] = 1.0f; v_s[i] = 1.0f; }
        __syncthreads();
        for (int it = 0; it < NITERS; it++) {
            {
                float sv = 0.f;
                for (int i = t; i < NROW; i += 1024) sv += v_s[i];
                for (int o = 32; o; o >>= 1) sv += __shfl_down(sv, o, 64);
                if (lane == 0) u_s[wid] = sv;
                __syncthreads();
                if (t < 64) {
                    float s2 = (t < 16) ? u_s[t] : 0.f;
                    for (int o = 8; o; o >>= 1) s2 += __shfl_down(s2, o, 64);
                    if (t == 0) u_s[0] = s2;
                }
                __syncthreads();
                float sum_v = u_s[0];
                __syncthreads();
                for (int i = t; i < NROW; i += 1024) u_s[i] = 1e-8f * sum_v;
                __syncthreads();
                for (int e = t; e < cnt; e += 1024)
                    atomicAdd(&u_s[list[e].i], list[e].s * v_s[list[e].j]);
                __syncthreads();
                for (int i = t; i < NROW; i += 1024) u_s[i] = AC / fmaxf(u_s[i], 1e-8f);
                __syncthreads();
            }
            {
                float su = 0.f;
                for (int i = t; i < NROW; i += 1024) su += u_s[i];
                for (int o = 32; o; o >>= 1) su += __shfl_down(su, o, 64);
                if (lane == 0) v_s[wid] = su;
                __syncthreads();
                if (t < 64) {
                    float s2 = (t < 16) ? v_s[t] : 0.f;
                    for (int o = 8; o; o >>= 1) s2 += __shfl_down(s2, o, 64);
                    if (t == 0) v_s[0] = s2;
                }
                __syncthreads();
                float sum_u = v_s[0];
                __syncthreads();
                for (int i = t; i < NROW; i += 1024) v_s[i] = 1e-8f * sum_u;
                __syncthreads();
                for (int e = t; e < cnt; e += 1024)
                    atomicAdd(&v_s[list[e].j], list[e].s * u_s[list[e].i]);
                __syncthreads();
                for (int i = t; i < NROW; i += 1024) v_s[i] = AC / fmaxf(v_s[i], 1e-8f);
                __syncthreads();
            }
        }
        for (int i = t; i < NROW; i += 1024) { up[i] = u_s[i]; vp[i] = v_s[i]; }
        if (t == 0) { acc[5] = 0.0; acc[6] = 0.0; acc[7] = 0.0; }
    }
}

// mega epilogue, 129 blocks/p x 64 rows: per-row frozen-base R iterations +
// Su/Sv/Sux2/Svy2/diag-sp + P,Q (LDS-combined -> 256 atomics/block);
// blockIdx.x==128 does the off-diag sparse correction; LAST finishing block
// (device atomic ctr) runs combine.
__global__ __launch_bounds__(256) void epi_k(const float* __restrict__ X,
                                             const float* __restrict__ Y,
                                             const float* __restrict__ x2,
                                             const float* __restrict__ y2,
                                             const float* __restrict__ sdiag,
                                             const float* __restrict__ tdiag,
                                             const float* __restrict__ u_g,
                                             const float* __restrict__ v_g,
                                             double* accum,
                                             int* counts,
                                             const Entry* __restrict__ lists,
                                             float* __restrict__ out) {
    int p = blockIdx.y;
    double* acc = accum + (size_t)p * 264;
    int t = threadIdx.x, lane = t & 63;
    int R = (int)acc[5];
    float bu = (float)acc[6], bv = (float)acc[7];

    if (blockIdx.x == 128) {
        // off-diag sparse correction; recompute final u_i, v_j per entry
        int cnt = counts[p]; if (cnt > CAP) cnt = CAP;
        const Entry* list = lists + (size_t)p * CAP;
        __shared__ double red[4];
        int wid = t >> 6;
        double sp_ = 0.0;
        for (int e = NROW + t; e < cnt; e += 256) {
            Entry en = list[e];
            if (en.t != 0.f) {
                float si = sdiag[p * NROW + en.i];
                float ui = u_g[p * NROW + en.i], vi = v_g[p * NROW + en.i];
                for (int it2 = 0; it2 < R; it2++) {
                    ui = AC * __builtin_amdgcn_rcpf(fmaxf(bv + si * vi, 1e-8f));
                    vi = AC * __builtin_amdgcn_rcpf(fmaxf(bu + si * ui, 1e-8f));
                }
                float sj = sdiag[p * NROW + en.j];
                float uj = u_g[p * NROW + en.j], vj = v_g[p * NROW + en.j];
                for (int it2 = 0; it2 < R; it2++) {
                    uj = AC * __builtin_amdgcn_rcpf(fmaxf(bv + sj * vj, 1e-8f));
                    vj = AC * __builtin_amdgcn_rcpf(fmaxf(bu + sj * uj, 1e-8f));
                }
                sp_ += (double)ui * (double)vj * (double)en.t;
            }
        }
        for (int o = 32; o; o >>= 1) sp_ += __shfl_down(sp_, o, 64);
        if (lane == 0) red[wid] = sp_;
        __syncthreads();
        if (t == 0) {
            double tot = red[0] + red[1] + red[2] + red[3];
            atomicAdd(&acc[4], tot);
        }
    } else {
        const float* A = (p == 2) ? Y : X;
        const float* B = (p == 0) ? Y : ((p == 1) ? X : Y);
        const float* na = (p == 2) ? y2 : x2;
        const float* nb = (p == 0) ? y2 : ((p == 1) ? x2 : y2);
        int rbase = blockIdx.x * 64;
        __shared__ float us[64], vs[64];
        __shared__ double redP[4][32][4], redQ[4][32][4];   // 8 KB
        if (t < 64) {
            int r = rbase + t;
            // frozen-base iterations for own row (old sinkwide_k)
            float srow = sdiag[p * NROW + r];
            float u = u_g[p * NROW + r], v = v_g[p * NROW + r];
            for (int it2 = 0; it2 < R; it2++) {
                u = AC * __builtin_amdgcn_rcpf(fmaxf(bv + srow * v, 1e-8f));
                v = AC * __builtin_amdgcn_rcpf(fmaxf(bu + srow * u, 1e-8f));
            }
            us[t] = u; vs[t] = v;
            double ui = u, vi = v;
            double a0 = ui, a1 = vi, a2 = ui * (double)na[r], a3 = vi * (double)nb[r];
            double a4 = ui * vi * (double)tdiag[p * NROW + r];
            for (int o = 32; o; o >>= 1) {
                a0 += __shfl_down(a0, o, 64); a1 += __shfl_down(a1, o, 64);
                a2 += __shfl_down(a2, o, 64); a3 += __shfl_down(a3, o, 64);
                a4 += __shfl_down(a4, o, 64);
            }
            if (lane == 0) {
                atomicAdd(&acc[0], a0); atomicAdd(&acc[1], a1);
                atomicAdd(&acc[2], a2); atomicAdd(&acc[3], a3);
                atomicAdd(&acc[4], a4);
            }
        }
        __syncthreads();
        {
            int dq = (t & 31) * 4, g = t >> 5;   // g in [0,8)
            int w = t >> 6;
            double pp[4] = {0, 0, 0, 0}, qq[4] = {0, 0, 0, 0};
            for (int k = 0; k < 8; k++) {
                int rr = g + 8 * k;              // [0,64)
                float4 av = *(const float4*)(A + (size_t)(rbase + rr) * DDIM + dq);
                float usv = us[rr];
                pp[0] += (double)usv * av.x; pp[1] += (double)usv * av.y;
                pp[2] += (double)usv * av.z; pp[3] += (double)usv * av.w;
                float4 bvv = *(const float4*)(B + (size_t)(rbase + rr) * DDIM + dq);
                float vsv = vs[rr];
                qq[0] += (double)vsv * bvv.x; qq[1] += (double)vsv * bvv.y;
                qq[2] += (double)vsv * bvv.z; qq[3] += (double)vsv * bvv.w;
            }
            #pragma unroll
            for (int m = 0; m < 4; m++) {
                pp[m] += __shfl_down(pp[m], 32, 64);
                qq[m] += __shfl_down(qq[m], 32, 64);
            }
            if (lane < 32) {
                #pragma unroll
                for (int m = 0; m < 4; m++) { redP[w][lane][m] = pp[m]; redQ[w][lane][m] = qq[m]; }
            }
            __syncthreads();
            // 256 threads: t<128 -> P[dq..], t>=128 -> Q[dq..]; one atomic each
            int q = t & 127, isQ = t >> 7;
            int dqi = q >> 2, m = q & 3;
            double sum = isQ ? (redQ[0][dqi][m] + redQ[1][dqi][m] + redQ[2][dqi][m] + redQ[3][dqi][m])
                             : (redP[0][dqi][m] + redP[1][dqi][m] + redP[2][dqi][m] + redP[3][dqi][m]);
            atomicAdd(&acc[(isQ ? 136 : 8) + q], sum);
        }
    }

    // ---- last-block combine ----
    __shared__ int lastFlag;
    __syncthreads();
    if (t == 0) {
        __threadfence();
        lastFlag = (atomicAdd(&counts[6], 1) == 386) ? 1 : 0;   // 129*3 blocks
    }
    __syncthreads();
    if (lastFlag) {
        __threadfence();
        __shared__ double costs[3];
        if (t < 64) {
            for (int p2 = 0; p2 < 3; p2++) {
                const double* ac2 = accum + (size_t)p2 * 264;
                double part = ald(ac2 + 8 + t) * ald(ac2 + 136 + t)
                            + ald(ac2 + 8 + 64 + t) * ald(ac2 + 136 + 64 + t);
                for (int o = 32; o; o >>= 1) part += __shfl_down(part, o, 64);
                if (t == 0) {
                    double F = ald(ac2 + 2) * ald(ac2 + 1) + ald(ac2 + 0) * ald(ac2 + 3) - 2.0 * part;
                    double c = 1e-8 * F + ald(ac2 + 4);
                    costs[p2] = (c > 0.0) ? c : 0.0;
                }
            }
        }
        __syncthreads();
        if (t == 0) {
            double dv = costs[0] - 0.5 * (costs[1] + costs[2]);
            dv = fmin(fmax(dv, 0.0), 10000.0);
            out[0] = (float)dv;
        }
    }
}

extern "C" void kernel_launch(void* const* d_in, const int* in_sizes, int n_in,
                              void* d_out, int out_size, void* d_ws, size_t ws_size,
                              hipStream_t stream) {
    const float* X = (const float*)d_in[0];
    const float* Y = (const float*)d_in[1];
    float* out = (float*)d_out;
    char* ws = (char*)d_ws;
    float* x2 = (float*)ws;
    float* y2 = (float*)(ws + 32768);
    float* x2p = (float*)(ws + 65536);
    float* y2p = (float*)(ws + 98304);
    int* counts = (int*)(ws + 131072);
    double* accum = (double*)(ws + 131136);
    Entry* lists = (Entry*)(ws + 137472);
    unsigned short* Xbf = (unsigned short*)(ws + 923904);
    unsigned short* Ybf = (unsigned short*)(ws + 1448192);
    float* sdiag = (float*)(ws + 1972480);
    float* tdiag = (float*)(ws + 2070784);
    float* u_g = (float*)(ws + 2169088);
    float* v_g = (float*)(ws + 2267392);

    norms_k<<<2048, 256, 0, stream>>>(X, Y, x2, y2, x2p, y2p, Xbf, Ybf, counts, accum, lists, sdiag, tdiag);
    scan_k<<<4160, 512, 0, stream>>>(Xbf, Ybf, x2p, y2p, counts, lists);
    sink2_k<<<3, 1024, 0, stream>>>(counts, lists, sdiag, u_g, v_g, accum, X, Y, x2, y2);
    epi_k<<<dim3(129, 3), 256, 0, stream>>>(X, Y, x2, y2, sdiag, tdiag, u_g, v_g, accum, counts, lists, out);
}

// Round 6
// 128.344 us; speedup vs baseline: 1.0692x; 1.0692x over previous
//
#include <hip/hip_runtime.h>
#include <math.h>

#define NROW 8192
#define DDIM 128
#define DP 32          // prescan dims (exact lower bound of full distance)
#define CAP 16384
#define NITERS 100
#define NWARM 6
#define AC (1.0f / 8192.0f)
#define LSTR 32        // linear LDS row stride (elems); slots XOR-swizzled

struct Entry { int i, j; float s, t; };

// ws layout (bytes), no overlays:
// 0        x2   float[NROW]
// 32768    y2   float[NROW]
// 65536    x2p  float[NROW]   partial norms (dims 0..31)
// 98304    y2p  float[NROW]
// 131072   counts int[8]      [0..2]=list counts, [6]=epi done-counter
// 131136   accum double[3][264]
// 137472   lists Entry[3][CAP]      -> 923904
// 923904   Xbf ushort[NROW*DP]      -> 1448192
// 1448192  Ybf ushort[NROW*DP]      -> 1972480
// 1972480  sdiag float[3*NROW]      -> 2070784
// 2070784  tdiag float[3*NROW]      -> 2169088
// 2169088  u_g  float[3*NROW]       -> 2267392
// 2267392  v_g  float[3*NROW]       -> 2365696

typedef __attribute__((ext_vector_type(8))) short frag_ab;   // 8 bf16
typedef __attribute__((ext_vector_type(4))) float frag_cd;   // 4 fp32

__device__ inline unsigned short f2bf(float f) {
    unsigned u = __float_as_uint(f);
    return (unsigned short)((u + 0x7FFFu + ((u >> 16) & 1u)) >> 16);  // RN-even
}

// shared arithmetic helpers (identical text everywhere -> identical rounding)
__device__ inline float wave_dot128(const float* __restrict__ ar, const float* __restrict__ br, int lane) {
    float dot = ar[lane] * br[lane] + ar[lane + 64] * br[lane + 64];
    for (int o = 32; o; o >>= 1) dot += __shfl_down(dot, o, 64);
    return dot;
}
__device__ inline void st_from_raw(float raw, float& s, float& tv) {
    float C = fmaxf(raw, 0.0f);
    float sc = fmaxf(-C * 100.0f, -50.0f);
    float K = fmaxf(expf(sc), 1e-8f);
    s = K - 1e-8f;
    tv = (raw >= 0.f) ? s * C : (-1e-8f) * raw;   // exactly 0 when s==0
}
__device__ inline double ald(const double* p) {
    return __hip_atomic_load(p, __ATOMIC_RELAXED, __HIP_MEMORY_SCOPE_AGENT);
}

// norms + partial norms + bf16(dims 0..31) + ALL diagonal s,t (p=0,1,2) + init.
// (round-4 split form: X-waves handle X_r + the p0 cross terms; Y-waves Y_r.)
__global__ void norms_k(const float* __restrict__ X, const float* __restrict__ Y,
                        float* __restrict__ x2, float* __restrict__ y2,
                        float* __restrict__ x2p, float* __restrict__ y2p,
                        unsigned short* __restrict__ Xbf, unsigned short* __restrict__ Ybf,
                        int* counts, double* accum, Entry* lists,
                        float* __restrict__ sdiag, float* __restrict__ tdiag) {
    int idx = blockIdx.x * 256 + threadIdx.x;
    if (idx < 3) counts[idx] = NROW;
    else if (idx < 8) counts[idx] = 0;
    if (idx < 3 * 264) accum[idx] = 0.0;
    int gw = idx >> 6;
    int lane = idx & 63;
    if (gw >= 2 * NROW) return;
    int isX = gw < NROW;
    int r = isX ? gw : gw - NROW;
    const float* M = isX ? X : Y;
    const float* ar = M + (size_t)r * DDIM;
    float* out = isX ? x2 : y2;
    float* outp = isX ? x2p : y2p;
    unsigned short* Mb = isX ? Xbf : Ybf;
    float2 v = *(const float2*)(ar + lane * 2);
    if (lane < 16) {
        unsigned pk = (unsigned)f2bf(v.x) | ((unsigned)f2bf(v.y) << 16);
        *(unsigned*)(Mb + (size_t)r * DP + lane * 2) = pk;
    }
    float s = v.x * v.x + v.y * v.y;
    float sp = (lane < 16) ? s : 0.f;
    for (int o = 32; o; o >>= 1) s += __shfl_down(s, o, 64);
    for (int o = 8; o; o >>= 1) sp += __shfl_down(sp, o, 64);
    // self-dot in exact layout (matches exact-path reduce order)
    float dself = wave_dot128(ar, ar, lane);
    if (isX) {
        const float* br = Y + (size_t)r * DDIM;
        float dxy = wave_dot128(ar, br, lane);
        float2 wv = *(const float2*)(br + lane * 2);
        float sy = wv.x * wv.x + wv.y * wv.y;
        for (int o = 32; o; o >>= 1) sy += __shfl_down(sy, o, 64);
        if (lane == 0) {
            out[r] = s; outp[r] = sp;
            float s1, t1; st_from_raw(s + s - 2.0f * dself, s1, t1);      // p=1 (X,X)
            sdiag[NROW + r] = s1; tdiag[NROW + r] = t1;
            Entry e1; e1.i = r; e1.j = r; e1.s = s1; e1.t = t1;
            lists[(size_t)CAP + r] = e1;
            float s0, t0; st_from_raw(s + sy - 2.0f * dxy, s0, t0);       // p=0 (X,Y)
            sdiag[r] = s0; tdiag[r] = t0;
            Entry e0; e0.i = r; e0.j = r; e0.s = s0; e0.t = t0;
            lists[r] = e0;
        }
    } else {
        if (lane == 0) {
            out[r] = s; outp[r] = sp;
            float s2, t2; st_from_raw(s + s - 2.0f * dself, s2, t2);      // p=2 (Y,Y)
            sdiag[2 * NROW + r] = s2; tdiag[2 * NROW + r] = t2;
            Entry e2; e2.i = r; e2.j = r; e2.s = s2; e2.t = t2;
            lists[(size_t)2 * CAP + r] = e2;
        }
    }
}

// MFMA prescan over dims 0..31, 256x128 tiles, 512 threads (8 waves of 64x64).
// Staging via global_load_lds width=16: linear LDS dest, per-lane PRE-SWIZZLED
// global source (global (row,q) -> LDS slot (row, q ^ ((row>>1)&3))), matching
// XOR on the ds_read side -> conflict-free b128 reads (8 distinct 16B slots per
// 8-lane phase). Same bits -> identical MFMA output -> identical listed set.
// Group filter: per 16-elem group, min(na,4rows)+min(yj,4cols)-2*max(acc,16) < 2
// escalates to the per-element test (monotone fp => identical listed set).
__global__ __launch_bounds__(512) void scan_k(const unsigned short* __restrict__ Xbf,
                                              const unsigned short* __restrict__ Ybf,
                                              const float* __restrict__ x2p,
                                              const float* __restrict__ y2p,
                                              int* counts, Entry* lists) {
    // flat decode: p0 = 32x64 tiles; p1/p2 upper wedge by >= 2bx (1056 each)
    int bid = blockIdx.x;
    int p, bx, by;
    if (bid < 2048) { p = 0; bx = bid >> 6; by = bid & 63; }
    else {
        int r = bid - 2048;
        p = 1 + (r >= 1056);
        int q = r - (p == 2) * 1056;
        int a = (int)((65.0f - sqrtf((float)(4225 - 4 * q))) * 0.5f);
        while (65 * a - a * a > q) a--;
        while (65 * (a + 1) - (a + 1) * (a + 1) <= q) a++;
        bx = a;
        by = 2 * a + (q - (65 * a - a * a));
    }
    const unsigned short* Ab = (p == 2) ? Ybf : Xbf;
    const unsigned short* Bb = (p == 0) ? Ybf : ((p == 1) ? Xbf : Ybf);
    const float* na = (p == 2) ? y2p : x2p;
    const float* nb = (p == 0) ? y2p : ((p == 1) ? x2p : y2p);
    int i0 = bx * 256, j0 = by * 128;

    __shared__ unsigned short As[256 * LSTR];   // 16 KB, linear
    __shared__ unsigned short Bs[128 * LSTR];   // 8 KB, linear
    __shared__ float sMinA[64];
    __shared__ float sNa[256];
    __shared__ float sNb[128];
    int t = threadIdx.x;

    const unsigned short* ga = Ab + (size_t)i0 * DP;
    const unsigned short* gb = Bb + (size_t)j0 * DP;
    // async global->LDS: dest linear (base + lane*16B), source pre-swizzled
    #pragma unroll
    for (int c = 0; c < 2; c++) {
        int u = c * 512 + t;
        int row = u >> 2, sq = u & 3;
        int q = sq ^ ((row >> 1) & 3);
        __builtin_amdgcn_global_load_lds(ga + (size_t)row * DP + q * 8,
                                         &As[(size_t)(u & ~63) * 8], 16, 0, 0);
    }
    {
        int row = t >> 2, sq = t & 3;
        int q = sq ^ ((row >> 1) & 3);
        __builtin_amdgcn_global_load_lds(gb + (size_t)row * DP + q * 8,
                                         &Bs[(size_t)(t & ~63) * 8], 16, 0, 0);
    }
    if (t < 256) sNa[t] = na[i0 + t];
    else if (t < 384) sNb[t - 256] = nb[j0 + (t - 256)];
    if (t < 64) {
        const float* nn = na + i0 + t * 4;
        sMinA[t] = fminf(fminf(nn[0], nn[1]), fminf(nn[2], nn[3]));
    }
    __syncthreads();

    int w = t >> 6, lane = t & 63;
    int lm = lane & 15, quad = lane >> 4;
    int wr = (w >> 1) * 64, wc = (w & 1) * 64;

    frag_cd acc[4][4];
    #pragma unroll
    for (int rt = 0; rt < 4; rt++)
        #pragma unroll
        for (int ct = 0; ct < 4; ct++) acc[rt][ct] = (frag_cd){0.f, 0.f, 0.f, 0.f};

    {
        frag_ab a[4], b[4];
        #pragma unroll
        for (int rt = 0; rt < 4; rt++) {
            int row = wr + rt * 16 + lm;
            a[rt] = *(const frag_ab*)&As[row * LSTR + ((quad ^ ((row >> 1) & 3)) << 3)];
        }
        #pragma unroll
        for (int ct = 0; ct < 4; ct++) {
            int row = wc + ct * 16 + lm;
            b[ct] = *(const frag_ab*)&Bs[row * LSTR + ((quad ^ ((row >> 1) & 3)) << 3)];
        }
        #pragma unroll
        for (int rt = 0; rt < 4; rt++)
            #pragma unroll
            for (int ct = 0; ct < 4; ct++)
                acc[rt][ct] = __builtin_amdgcn_mfma_f32_16x16x32_bf16(a[rt], b[ct], acc[rt][ct], 0, 0, 0);
    }

    Entry* list = lists + (size_t)p * CAP;
    float yj_[4];
    #pragma unroll
    for (int ct = 0; ct < 4; ct++) yj_[ct] = sNb[wc + ct * 16 + lm];
    float minyj = fminf(fminf(yj_[0], yj_[1]), fminf(yj_[2], yj_[3]));

    #pragma unroll
    for (int rt = 0; rt < 4; rt++) {
        float m0 = fmaxf(fmaxf(acc[rt][0][0], acc[rt][0][1]), fmaxf(acc[rt][0][2], acc[rt][0][3]));
        float m1 = fmaxf(fmaxf(acc[rt][1][0], acc[rt][1][1]), fmaxf(acc[rt][1][2], acc[rt][1][3]));
        float m2 = fmaxf(fmaxf(acc[rt][2][0], acc[rt][2][1]), fmaxf(acc[rt][2][2], acc[rt][2][3]));
        float m3 = fmaxf(fmaxf(acc[rt][3][0], acc[rt][3][1]), fmaxf(acc[rt][3][2], acc[rt][3][3]));
        float mx = fmaxf(fmaxf(m0, m1), fmaxf(m2, m3));
        float mna = sMinA[(wr >> 2) + rt * 4 + quad];
        if (mna + minyj - 2.f * mx < 2.0f) {
            #pragma unroll
            for (int ct = 0; ct < 4; ct++) {
                int j = j0 + wc + ct * 16 + lm;
                float yj = yj_[ct];
                #pragma unroll
                for (int reg = 0; reg < 4; reg++) {
                    int li = wr + rt * 16 + quad * 4 + reg;
                    int i = i0 + li;
                    float Ct = sNa[li] + yj - 2.f * acc[rt][ct][reg];
                    if (Ct < 2.0f && i != j) {
                        if (p == 0) {
                            int idx = atomicAdd(&counts[0], 1);
                            if (idx < CAP) { Entry e; e.i = i; e.j = j; e.s = 0.f; e.t = 0.f; list[idx] = e; }
                        } else if (i < j) {
                            int idx = atomicAdd(&counts[p], 2);
                            if (idx < CAP) { Entry e; e.i = i; e.j = j; e.s = 0.f; e.t = 0.f; list[idx] = e; }
                            if (idx + 1 < CAP) { Entry e; e.i = j; e.j = i; e.s = 0.f; e.t = 0.f; list[idx + 1] = e; }
                        }
                    }
                }
            }
        }
    }
}

// sink2: (1) folded exact pass for off-diag listed entries (usually empty),
// (2) warm Sinkhorn + freeze, or full fallback when off-diag active entries exist.
__global__ __launch_bounds__(1024, 1) void sink2_k(const int* counts,
                                                   Entry* lists,
                                                   const float* __restrict__ sdiag,
                                                   float* __restrict__ u_g,
                                                   float* __restrict__ v_g,
                                                   double* accum,
                                                   const float* __restrict__ X,
                                                   const float* __restrict__ Y,
                                                   const float* __restrict__ x2,
                                                   const float* __restrict__ y2) {
    int p = blockIdx.x;
    Entry* listm = lists + (size_t)p * CAP;
    const Entry* list = listm;
    int cnt = counts[p]; if (cnt > CAP) cnt = CAP;
    double* acc = accum + (size_t)p * 264;
    float* up = u_g + (size_t)p * NROW;
    float* vp = v_g + (size_t)p * NROW;

    __shared__ float u_s[NROW];   // fallback only
    __shared__ float v_s[NROW];
    __shared__ float redS[2][16];
    __shared__ unsigned redC[16];
    __shared__ int nres_s;
    int t = threadIdx.x;
    int wid = t >> 6, lane = t & 63;

    // ---- folded exact: off-diagonal entries [NROW, cnt) ----
    if (t == 0) nres_s = 0;
    __syncthreads();
    {
        const float* A = (p == 2) ? Y : X;
        const float* B = (p == 0) ? Y : ((p == 1) ? X : Y);
        const float* na = (p == 2) ? y2 : x2;
        const float* nb = (p == 0) ? y2 : ((p == 1) ? x2 : y2);
        int act = 0;
        for (int e = NROW + wid; e < cnt; e += 16) {
            int i = listm[e].i, j = listm[e].j;
            float dot = wave_dot128(A + (size_t)i * DDIM, B + (size_t)j * DDIM, lane);
            if (lane == 0) {
                float raw = na[i] + nb[j] - 2.0f * dot;
                float s, tv; st_from_raw(raw, s, tv);
                listm[e].s = s; listm[e].t = tv;
                if (s != 0.f || tv != 0.f) act++;
            }
        }
        if (lane == 0 && act) atomicAdd(&nres_s, act);
    }
    __syncthreads();
    int nres = nres_s;

    if (nres == 0) {
        float vk[8], uk[8], sk[8];
        unsigned pv2[8];
        #pragma unroll
        for (int k = 0; k < 8; k++) {
            sk[k] = sdiag[p * NROW + t + 1024 * k];
            vk[k] = 1.0f; uk[k] = AC; pv2[k] = 0xFFFFFFFFu;
        }
        unsigned flags = 3u;
        int par = 0, last = 0, done = 0;
        float bu_last = 0.f;
        for (int it = 0; it < NWARM; it++) {
            float s = 0.f;
            #pragma unroll
            for (int k = 0; k < 8; k++) s += vk[k];
            for (int o = 32; o; o >>= 1) s += __shfl_down(s, o, 64);
            if (lane == 0) { redS[par][wid] = s; redC[wid] = flags; }
            __syncthreads();
            float sumv = 0.f; unsigned anyf = 0;
            #pragma unroll
            for (int w2 = 0; w2 < 16; w2++) { sumv += redS[par][w2]; anyf |= redC[w2]; }
            par ^= 1;
            if (it > 0) {
                if (!(anyf & 1)) { done = 1; break; }
                if (!(anyf & 2)) {
                    if (((NITERS - it) & 1) == 0) { done = 1; break; }
                    last = 1;
                }
            }
            float base = 1e-8f * sumv;
            #pragma unroll
            for (int k = 0; k < 8; k++) {
                float kv = fmaxf(base + sk[k] * vk[k], 1e-8f);
                uk[k] = AC * __builtin_amdgcn_rcpf(kv);
            }
            s = 0.f;
            #pragma unroll
            for (int k = 0; k < 8; k++) s += uk[k];
            for (int o = 32; o; o >>= 1) s += __shfl_down(s, o, 64);
            if (lane == 0) redS[par][wid] = s;
            __syncthreads();
            float sumu = 0.f;
            #pragma unroll
            for (int w2 = 0; w2 < 16; w2++) sumu += redS[par][w2];
            par ^= 1;
            base = 1e-8f * sumu;
            bu_last = base;
            unsigned d1 = 0, d2 = 0;
            #pragma unroll
            for (int k = 0; k < 8; k++) {
                float kv = fmaxf(base + sk[k] * uk[k], 1e-8f);
                float nv = AC * __builtin_amdgcn_rcpf(kv);
                unsigned nb_ = __float_as_uint(nv);
                d1 |= nb_ ^ __float_as_uint(vk[k]);
                d2 |= nb_ ^ pv2[k];
                pv2[k] = __float_as_uint(vk[k]);
                vk[k] = nv;
            }
            flags = (__any(d1 != 0) ? 1u : 0u) | (__any(d2 != 0) ? 2u : 0u);
            if (last) { done = 1; break; }
        }
        float bv_f = 0.f;
        int R = 0;
        if (!done) {
            float s = 0.f;
            #pragma unroll
            for (int k = 0; k < 8; k++) s += vk[k];
            for (int o = 32; o; o >>= 1) s += __shfl_down(s, o, 64);
            if (lane == 0) redS[par][wid] = s;
            __syncthreads();
            float sumv = 0.f;
            #pragma unroll
            for (int w2 = 0; w2 < 16; w2++) sumv += redS[par][w2];
            bv_f = 1e-8f * sumv;
            R = NITERS - NWARM;
        }
        #pragma unroll
        for (int k = 0; k < 8; k++) {
            int i = t + 1024 * k;
            up[i] = uk[k]; vp[i] = vk[k];
        }
        if (t == 0) { acc[5] = (double)R; acc[6] = (double)bu_last; acc[7] = (double)bv_f; }
    } else {
        // -------- fallback: general sparse scatter, full 100 iterations --------
        for (int i = t; i < NROW; i += 1024) { u_s[i] = 1.0f; v_s[i] = 1.0f; }
        __syncthreads();
        for (int it = 0; it < NITERS; it++) {
            {
                float sv = 0.f;
                for (int i = t; i < NROW; i += 1024) sv += v_s[i];
                for (int o = 32; o; o >>= 1) sv += __shfl_down(sv, o, 64);
                if (lane == 0) u_s[wid] = sv;
                __syncthreads();
                if (t < 64) {
                    float s2 = (t < 16) ? u_s[t] : 0.f;
                    for (int o = 8; o; o >>= 1) s2 += __shfl_down(s2, o, 64);
                    if (t == 0) u_s[0] = s2;
                }
                __syncthreads();
                float sum_v = u_s[0];
                __syncthreads();
                for (int i = t; i < NROW; i += 1024) u_s[i] = 1e-8f * sum_v;
                __syncthreads();
                for (int e = t; e < cnt; e += 1024)
                    atomicAdd(&u_s[list[e].i], list[e].s * v_s[list[e].j]);
                __syncthreads();
                for (int i = t; i < NROW; i += 1024) u_s[i] = AC / fmaxf(u_s[i], 1e-8f);
                __syncthreads();
            }
            {
                float su = 0.f;
                for (int i = t; i < NROW; i += 1024) su += u_s[i];
                for (int o = 32; o; o >>= 1) su += __shfl_down(su, o, 64);
                if (lane == 0) v_s[wid] = su;
                __syncthreads();
                if (t < 64) {
                    float s2 = (t < 16) ? v_s[t] : 0.f;
                    for (int o = 8; o; o >>= 1) s2 += __shfl_down(s2, o, 64);
                    if (t == 0) v_s[0] = s2;
                }
                __syncthreads();
                float sum_u = v_s[0];
                __syncthreads();
                for (int i = t; i < NROW; i += 1024) v_s[i] = 1e-8f * sum_u;
                __syncthreads();
                for (int e = t; e < cnt; e += 1024)
                    atomicAdd(&v_s[list[e].j], list[e].s * u_s[list[e].i]);
                __syncthreads();
                for (int i = t; i < NROW; i += 1024) v_s[i] = AC / fmaxf(v_s[i], 1e-8f);
                __syncthreads();
            }
        }
        for (int i = t; i < NROW; i += 1024) { up[i] = u_s[i]; vp[i] = v_s[i]; }
        if (t == 0) { acc[5] = 0.0; acc[6] = 0.0; acc[7] = 0.0; }
    }
}

// mega epilogue, 129 blocks/p x 64 rows: per-row frozen-base R iterations +
// Su/Sv/Sux2/Svy2/diag-sp + P,Q (LDS-combined -> 256 atomics/block);
// blockIdx.x==128 does the off-diag sparse correction; LAST finishing block
// (device atomic ctr) runs combine.
__global__ __launch_bounds__(256) void epi_k(const float* __restrict__ X,
                                             const float* __restrict__ Y,
                                             const float* __restrict__ x2,
                                             const float* __restrict__ y2,
                                             const float* __restrict__ sdiag,
                                             const float* __restrict__ tdiag,
                                             const float* __restrict__ u_g,
                                             const float* __restrict__ v_g,
                                             double* accum,
                                             int* counts,
                                             const Entry* __restrict__ lists,
                                             float* __restrict__ out) {
    int p = blockIdx.y;
    double* acc = accum + (size_t)p * 264;
    int t = threadIdx.x, lane = t & 63;
    int R = (int)acc[5];
    float bu = (float)acc[6], bv = (float)acc[7];

    if (blockIdx.x == 128) {
        // off-diag sparse correction; recompute final u_i, v_j per entry
        int cnt = counts[p]; if (cnt > CAP) cnt = CAP;
        const Entry* list = lists + (size_t)p * CAP;
        __shared__ double red[4];
        int wid = t >> 6;
        double sp_ = 0.0;
        for (int e = NROW + t; e < cnt; e += 256) {
            Entry en = list[e];
            if (en.t != 0.f) {
                float si = sdiag[p * NROW + en.i];
                float ui = u_g[p * NROW + en.i], vi = v_g[p * NROW + en.i];
                for (int it2 = 0; it2 < R; it2++) {
                    ui = AC * __builtin_amdgcn_rcpf(fmaxf(bv + si * vi, 1e-8f));
                    vi = AC * __builtin_amdgcn_rcpf(fmaxf(bu + si * ui, 1e-8f));
                }
                float sj = sdiag[p * NROW + en.j];
                float uj = u_g[p * NROW + en.j], vj = v_g[p * NROW + en.j];
                for (int it2 = 0; it2 < R; it2++) {
                    uj = AC * __builtin_amdgcn_rcpf(fmaxf(bv + sj * vj, 1e-8f));
                    vj = AC * __builtin_amdgcn_rcpf(fmaxf(bu + sj * uj, 1e-8f));
                }
                sp_ += (double)ui * (double)vj * (double)en.t;
            }
        }
        for (int o = 32; o; o >>= 1) sp_ += __shfl_down(sp_, o, 64);
        if (lane == 0) red[wid] = sp_;
        __syncthreads();
        if (t == 0) {
            double tot = red[0] + red[1] + red[2] + red[3];
            atomicAdd(&acc[4], tot);
        }
    } else {
        const float* A = (p == 2) ? Y : X;
        const float* B = (p == 0) ? Y : ((p == 1) ? X : Y);
        const float* na = (p == 2) ? y2 : x2;
        const float* nb = (p == 0) ? y2 : ((p == 1) ? x2 : y2);
        int rbase = blockIdx.x * 64;
        __shared__ float us[64], vs[64];
        __shared__ double redP[4][32][4], redQ[4][32][4];   // 8 KB
        if (t < 64) {
            int r = rbase + t;
            // frozen-base iterations for own row (old sinkwide_k)
            float srow = sdiag[p * NROW + r];
            float u = u_g[p * NROW + r], v = v_g[p * NROW + r];
            for (int it2 = 0; it2 < R; it2++) {
                u = AC * __builtin_amdgcn_rcpf(fmaxf(bv + srow * v, 1e-8f));
                v = AC * __builtin_amdgcn_rcpf(fmaxf(bu + srow * u, 1e-8f));
            }
            us[t] = u; vs[t] = v;
            double ui = u, vi = v;
            double a0 = ui, a1 = vi, a2 = ui * (double)na[r], a3 = vi * (double)nb[r];
            double a4 = ui * vi * (double)tdiag[p * NROW + r];
            for (int o = 32; o; o >>= 1) {
                a0 += __shfl_down(a0, o, 64); a1 += __shfl_down(a1, o, 64);
                a2 += __shfl_down(a2, o, 64); a3 += __shfl_down(a3, o, 64);
                a4 += __shfl_down(a4, o, 64);
            }
            if (lane == 0) {
                atomicAdd(&acc[0], a0); atomicAdd(&acc[1], a1);
                atomicAdd(&acc[2], a2); atomicAdd(&acc[3], a3);
                atomicAdd(&acc[4], a4);
            }
        }
        __syncthreads();
        {
            int dq = (t & 31) * 4, g = t >> 5;   // g in [0,8)
            int w = t >> 6;
            double pp[4] = {0, 0, 0, 0}, qq[4] = {0, 0, 0, 0};
            for (int k = 0; k < 8; k++) {
                int rr = g + 8 * k;              // [0,64)
                float4 av = *(const float4*)(A + (size_t)(rbase + rr) * DDIM + dq);
                float usv = us[rr];
                pp[0] += (double)usv * av.x; pp[1] += (double)usv * av.y;
                pp[2] += (double)usv * av.z; pp[3] += (double)usv * av.w;
                float4 bvv = *(const float4*)(B + (size_t)(rbase + rr) * DDIM + dq);
                float vsv = vs[rr];
                qq[0] += (double)vsv * bvv.x; qq[1] += (double)vsv * bvv.y;
                qq[2] += (double)vsv * bvv.z; qq[3] += (double)vsv * bvv.w;
            }
            #pragma unroll
            for (int m = 0; m < 4; m++) {
                pp[m] += __shfl_down(pp[m], 32, 64);
                qq[m] += __shfl_down(qq[m], 32, 64);
            }
            if (lane < 32) {
                #pragma unroll
                for (int m = 0; m < 4; m++) { redP[w][lane][m] = pp[m]; redQ[w][lane][m] = qq[m]; }
            }
            __syncthreads();
            // 256 threads: t<128 -> P[dq..], t>=128 -> Q[dq..]; one atomic each
            int q = t & 127, isQ = t >> 7;
            int dqi = q >> 2, m = q & 3;
            double sum = isQ ? (redQ[0][dqi][m] + redQ[1][dqi][m] + redQ[2][dqi][m] + redQ[3][dqi][m])
                             : (redP[0][dqi][m] + redP[1][dqi][m] + redP[2][dqi][m] + redP[3][dqi][m]);
            atomicAdd(&acc[(isQ ? 136 : 8) + q], sum);
        }
    }

    // ---- last-block combine ----
    __shared__ int lastFlag;
    __syncthreads();
    if (t == 0) {
        __threadfence();
        lastFlag = (atomicAdd(&counts[6], 1) == 386) ? 1 : 0;   // 129*3 blocks
    }
    __syncthreads();
    if (lastFlag) {
        __threadfence();
        __shared__ double costs[3];
        if (t < 64) {
            for (int p2 = 0; p2 < 3; p2++) {
                const double* ac2 = accum + (size_t)p2 * 264;
                double part = ald(ac2 + 8 + t) * ald(ac2 + 136 + t)
                            + ald(ac2 + 8 + 64 + t) * ald(ac2 + 136 + 64 + t);
                for (int o = 32; o; o >>= 1) part += __shfl_down(part, o, 64);
                if (t == 0) {
                    double F = ald(ac2 + 2) * ald(ac2 + 1) + ald(ac2 + 0) * ald(ac2 + 3) - 2.0 * part;
                    double c = 1e-8 * F + ald(ac2 + 4);
                    costs[p2] = (c > 0.0) ? c : 0.0;
                }
            }
        }
        __syncthreads();
        if (t == 0) {
            double dv = costs[0] - 0.5 * (costs[1] + costs[2]);
            dv = fmin(fmax(dv, 0.0), 10000.0);
            out[0] = (float)dv;
        }
    }
}

extern "C" void kernel_launch(void* const* d_in, const int* in_sizes, int n_in,
                              void* d_out, int out_size, void* d_ws, size_t ws_size,
                              hipStream_t stream) {
    const float* X = (const float*)d_in[0];
    const float* Y = (const float*)d_in[1];
    float* out = (float*)d_out;
    char* ws = (char*)d_ws;
    float* x2 = (float*)ws;
    float* y2 = (float*)(ws + 32768);
    float* x2p = (float*)(ws + 65536);
    float* y2p = (float*)(ws + 98304);
    int* counts = (int*)(ws + 131072);
    double* accum = (double*)(ws + 131136);
    Entry* lists = (Entry*)(ws + 137472);
    unsigned short* Xbf = (unsigned short*)(ws + 923904);
    unsigned short* Ybf = (unsigned short*)(ws + 1448192);
    float* sdiag = (float*)(ws + 1972480);
    float* tdiag = (float*)(ws + 2070784);
    float* u_g = (float*)(ws + 2169088);
    float* v_g = (float*)(ws + 2267392);

    norms_k<<<4096, 256, 0, stream>>>(X, Y, x2, y2, x2p, y2p, Xbf, Ybf, counts, accum, lists, sdiag, tdiag);
    scan_k<<<4160, 512, 0, stream>>>(Xbf, Ybf, x2p, y2p, counts, lists);
    sink2_k<<<3, 1024, 0, stream>>>(counts, lists, sdiag, u_g, v_g, accum, X, Y, x2, y2);
    epi_k<<<dim3(129, 3), 256, 0, stream>>>(X, Y, x2, y2, sdiag, tdiag, u_g, v_g, accum, counts, lists, out);
}

// Round 7
// 127.164 us; speedup vs baseline: 1.0791x; 1.0093x over previous
//
#include <hip/hip_runtime.h>
#include <math.h>

#define NROW 8192
#define DDIM 128
#define DP 32          // prescan dims (exact lower bound of full distance)
#define CAP 16384
#define NITERS 100
#define NWARM 6
#define AC (1.0f / 8192.0f)
#define LSTR 32        // linear LDS row stride (elems); slots XOR-swizzled

struct Entry { int i, j; float s, t; };

// ws layout (bytes), no overlays:
// 0        x2   float[NROW]
// 32768    y2   float[NROW]
// 65536    x2p  float[NROW]   partial norms (dims 0..31)
// 98304    y2p  float[NROW]
// 131072   counts int[8]      [0..2]=list counts, [6]=epi done-counter
// 131136   accum double[3][264]
// 137472   lists Entry[3][CAP]      -> 923904
// 923904   Xbf ushort[NROW*DP]      -> 1448192
// 1448192  Ybf ushort[NROW*DP]      -> 1972480
// 1972480  sdiag float[3*NROW]      -> 2070784
// 2070784  tdiag float[3*NROW]      -> 2169088
// 2169088  u_g  float[3*NROW]       -> 2267392
// 2267392  v_g  float[3*NROW]       -> 2365696

typedef __attribute__((ext_vector_type(8))) short frag_ab;   // 8 bf16
typedef __attribute__((ext_vector_type(4))) float frag_cd;   // 4 fp32

__device__ inline unsigned short f2bf(float f) {
    unsigned u = __float_as_uint(f);
    return (unsigned short)((u + 0x7FFFu + ((u >> 16) & 1u)) >> 16);  // RN-even
}

// shared arithmetic helpers (identical text everywhere -> identical rounding)
__device__ inline float wave_dot128(const float* __restrict__ ar, const float* __restrict__ br, int lane) {
    float dot = ar[lane] * br[lane] + ar[lane + 64] * br[lane + 64];
    for (int o = 32; o; o >>= 1) dot += __shfl_down(dot, o, 64);
    return dot;
}
__device__ inline void st_from_raw(float raw, float& s, float& tv) {
    float C = fmaxf(raw, 0.0f);
    float sc = fmaxf(-C * 100.0f, -50.0f);
    float K = fmaxf(expf(sc), 1e-8f);
    s = K - 1e-8f;
    tv = (raw >= 0.f) ? s * C : (-1e-8f) * raw;   // exactly 0 when s==0
}
__device__ inline double ald(const double* p) {
    return __hip_atomic_load(p, __ATOMIC_RELAXED, __HIP_MEMORY_SCOPE_AGENT);
}

// norms + partial norms + bf16(dims 0..31) + ALL diagonal s,t (p=0,1,2) + init.
__global__ void norms_k(const float* __restrict__ X, const float* __restrict__ Y,
                        float* __restrict__ x2, float* __restrict__ y2,
                        float* __restrict__ x2p, float* __restrict__ y2p,
                        unsigned short* __restrict__ Xbf, unsigned short* __restrict__ Ybf,
                        int* counts, double* accum, Entry* lists,
                        float* __restrict__ sdiag, float* __restrict__ tdiag) {
    int idx = blockIdx.x * 256 + threadIdx.x;
    if (idx < 3) counts[idx] = NROW;
    else if (idx < 8) counts[idx] = 0;
    if (idx < 3 * 264) accum[idx] = 0.0;
    int gw = idx >> 6;
    int lane = idx & 63;
    if (gw >= 2 * NROW) return;
    int isX = gw < NROW;
    int r = isX ? gw : gw - NROW;
    const float* M = isX ? X : Y;
    const float* ar = M + (size_t)r * DDIM;
    float* out = isX ? x2 : y2;
    float* outp = isX ? x2p : y2p;
    unsigned short* Mb = isX ? Xbf : Ybf;
    float2 v = *(const float2*)(ar + lane * 2);
    if (lane < 16) {
        unsigned pk = (unsigned)f2bf(v.x) | ((unsigned)f2bf(v.y) << 16);
        *(unsigned*)(Mb + (size_t)r * DP + lane * 2) = pk;
    }
    float s = v.x * v.x + v.y * v.y;
    float sp = (lane < 16) ? s : 0.f;
    for (int o = 32; o; o >>= 1) s += __shfl_down(s, o, 64);
    for (int o = 8; o; o >>= 1) sp += __shfl_down(sp, o, 64);
    // self-dot in exact layout (matches exact-path reduce order)
    float dself = wave_dot128(ar, ar, lane);
    if (isX) {
        const float* br = Y + (size_t)r * DDIM;
        float dxy = wave_dot128(ar, br, lane);
        float2 wv = *(const float2*)(br + lane * 2);
        float sy = wv.x * wv.x + wv.y * wv.y;
        for (int o = 32; o; o >>= 1) sy += __shfl_down(sy, o, 64);
        if (lane == 0) {
            out[r] = s; outp[r] = sp;
            float s1, t1; st_from_raw(s + s - 2.0f * dself, s1, t1);      // p=1 (X,X)
            sdiag[NROW + r] = s1; tdiag[NROW + r] = t1;
            Entry e1; e1.i = r; e1.j = r; e1.s = s1; e1.t = t1;
            lists[(size_t)CAP + r] = e1;
            float s0, t0; st_from_raw(s + sy - 2.0f * dxy, s0, t0);       // p=0 (X,Y)
            sdiag[r] = s0; tdiag[r] = t0;
            Entry e0; e0.i = r; e0.j = r; e0.s = s0; e0.t = t0;
            lists[r] = e0;
        }
    } else {
        if (lane == 0) {
            out[r] = s; outp[r] = sp;
            float s2, t2; st_from_raw(s + s - 2.0f * dself, s2, t2);      // p=2 (Y,Y)
            sdiag[2 * NROW + r] = s2; tdiag[2 * NROW + r] = t2;
            Entry e2; e2.i = r; e2.j = r; e2.s = s2; e2.t = t2;
            lists[(size_t)2 * CAP + r] = e2;
        }
    }
}

// MFMA prescan over dims 0..31, 256x256 tiles (two 128-col halves per block),
// 512 threads (8 waves of 64x64, each wave does 2 column-halves sequentially).
// Staging via global_load_lds width=16: linear LDS dest, per-lane PRE-SWIZZLED
// global source (global (row,q) -> LDS slot (row, q ^ ((row>>1)&3))), matching
// XOR on the ds_read side -> conflict-free b128 reads. Same bits -> identical
// MFMA output -> identical listed set.
// Group filter: per 16-elem group, min(na,4rows)+min(yj,4cols)-2*max(acc,16) < 2
// escalates to the per-element test (monotone fp => identical listed set).
__global__ __launch_bounds__(512) void scan_k(const unsigned short* __restrict__ Xbf,
                                              const unsigned short* __restrict__ Ybf,
                                              const float* __restrict__ x2p,
                                              const float* __restrict__ y2p,
                                              int* counts, Entry* lists) {
    // flat decode: p0 = 32x32 tiles; p1/p2 upper triangle by >= bx (528 each)
    int bid = blockIdx.x;
    int p, bx, by;
    if (bid < 1024) { p = 0; bx = bid >> 5; by = bid & 31; }
    else {
        int r = bid - 1024;
        p = 1 + (r >= 528);
        int q = r - (p == 2) * 528;
        // off(a) = a*(65-a)/2; find a with off(a) <= q < off(a+1)
        int a = (int)((65.0f - sqrtf((float)(4225 - 8 * q))) * 0.5f);
        while (a * (65 - a) / 2 > q) a--;
        while ((a + 1) * (64 - a) / 2 <= q) a++;
        bx = a;
        by = a + (q - a * (65 - a) / 2);
    }
    const unsigned short* Ab = (p == 2) ? Ybf : Xbf;
    const unsigned short* Bb = (p == 0) ? Ybf : ((p == 1) ? Xbf : Ybf);
    const float* na = (p == 2) ? y2p : x2p;
    const float* nb = (p == 0) ? y2p : ((p == 1) ? x2p : y2p);
    int i0 = bx * 256, j0 = by * 256;

    __shared__ unsigned short As[256 * LSTR];   // 16 KB, linear
    __shared__ unsigned short Bs[256 * LSTR];   // 16 KB, linear
    __shared__ float sMinA[64];
    __shared__ float sNa[256];
    __shared__ float sNb[256];
    int t = threadIdx.x;

    const unsigned short* ga = Ab + (size_t)i0 * DP;
    const unsigned short* gb = Bb + (size_t)j0 * DP;
    // async global->LDS: dest linear (base + lane*16B), source pre-swizzled
    #pragma unroll
    for (int c = 0; c < 2; c++) {
        int u = c * 512 + t;
        int row = u >> 2, sq = u & 3;
        int q = sq ^ ((row >> 1) & 3);
        __builtin_amdgcn_global_load_lds(ga + (size_t)row * DP + q * 8,
                                         &As[(size_t)(u & ~63) * 8], 16, 0, 0);
    }
    #pragma unroll
    for (int c = 0; c < 2; c++) {
        int u = c * 512 + t;
        int row = u >> 2, sq = u & 3;
        int q = sq ^ ((row >> 1) & 3);
        __builtin_amdgcn_global_load_lds(gb + (size_t)row * DP + q * 8,
                                         &Bs[(size_t)(u & ~63) * 8], 16, 0, 0);
    }
    if (t < 256) sNa[t] = na[i0 + t];
    else sNb[t - 256] = nb[j0 + (t - 256)];
    if (t < 64) {
        const float* nn = na + i0 + t * 4;
        sMinA[t] = fminf(fminf(nn[0], nn[1]), fminf(nn[2], nn[3]));
    }
    __syncthreads();

    int w = t >> 6, lane = t & 63;
    int lm = lane & 15, quad = lane >> 4;
    int wr = (w >> 1) * 64;

    frag_ab a[4];
    #pragma unroll
    for (int rt = 0; rt < 4; rt++) {
        int row = wr + rt * 16 + lm;
        a[rt] = *(const frag_ab*)&As[row * LSTR + ((quad ^ ((row >> 1) & 3)) << 3)];
    }

    Entry* list = lists + (size_t)p * CAP;

    #pragma unroll
    for (int half = 0; half < 2; half++) {
        int wc = (w & 1) * 64 + half * 128;
        frag_ab b[4];
        #pragma unroll
        for (int ct = 0; ct < 4; ct++) {
            int row = wc + ct * 16 + lm;
            b[ct] = *(const frag_ab*)&Bs[row * LSTR + ((quad ^ ((row >> 1) & 3)) << 3)];
        }
        frag_cd acc[4][4];
        #pragma unroll
        for (int rt = 0; rt < 4; rt++)
            #pragma unroll
            for (int ct = 0; ct < 4; ct++) acc[rt][ct] = (frag_cd){0.f, 0.f, 0.f, 0.f};
        #pragma unroll
        for (int rt = 0; rt < 4; rt++)
            #pragma unroll
            for (int ct = 0; ct < 4; ct++)
                acc[rt][ct] = __builtin_amdgcn_mfma_f32_16x16x32_bf16(a[rt], b[ct], acc[rt][ct], 0, 0, 0);

        float yj_[4];
        #pragma unroll
        for (int ct = 0; ct < 4; ct++) yj_[ct] = sNb[wc + ct * 16 + lm];
        float minyj = fminf(fminf(yj_[0], yj_[1]), fminf(yj_[2], yj_[3]));

        #pragma unroll
        for (int rt = 0; rt < 4; rt++) {
            float m0 = fmaxf(fmaxf(acc[rt][0][0], acc[rt][0][1]), fmaxf(acc[rt][0][2], acc[rt][0][3]));
            float m1 = fmaxf(fmaxf(acc[rt][1][0], acc[rt][1][1]), fmaxf(acc[rt][1][2], acc[rt][1][3]));
            float m2 = fmaxf(fmaxf(acc[rt][2][0], acc[rt][2][1]), fmaxf(acc[rt][2][2], acc[rt][2][3]));
            float m3 = fmaxf(fmaxf(acc[rt][3][0], acc[rt][3][1]), fmaxf(acc[rt][3][2], acc[rt][3][3]));
            float mx = fmaxf(fmaxf(m0, m1), fmaxf(m2, m3));
            float mna = sMinA[(wr >> 2) + rt * 4 + quad];
            if (mna + minyj - 2.f * mx < 2.0f) {
                #pragma unroll
                for (int ct = 0; ct < 4; ct++) {
                    int j = j0 + wc + ct * 16 + lm;
                    float yj = yj_[ct];
                    #pragma unroll
                    for (int reg = 0; reg < 4; reg++) {
                        int li = wr + rt * 16 + quad * 4 + reg;
                        int i = i0 + li;
                        float Ct = sNa[li] + yj - 2.f * acc[rt][ct][reg];
                        if (Ct < 2.0f && i != j) {
                            if (p == 0) {
                                int idx = atomicAdd(&counts[0], 1);
                                if (idx < CAP) { Entry e; e.i = i; e.j = j; e.s = 0.f; e.t = 0.f; list[idx] = e; }
                            } else if (i < j) {
                                int idx = atomicAdd(&counts[p], 2);
                                if (idx < CAP) { Entry e; e.i = i; e.j = j; e.s = 0.f; e.t = 0.f; list[idx] = e; }
                                if (idx + 1 < CAP) { Entry e; e.i = j; e.j = i; e.s = 0.f; e.t = 0.f; list[idx + 1] = e; }
                            }
                        }
                    }
                }
            }
        }
    }
}

// sink2: (1) folded exact pass for off-diag listed entries (usually empty),
// (2) warm Sinkhorn + freeze, or full fallback when off-diag active entries exist.
__global__ __launch_bounds__(1024, 1) void sink2_k(const int* counts,
                                                   Entry* lists,
                                                   const float* __restrict__ sdiag,
                                                   float* __restrict__ u_g,
                                                   float* __restrict__ v_g,
                                                   double* accum,
                                                   const float* __restrict__ X,
                                                   const float* __restrict__ Y,
                                                   const float* __restrict__ x2,
                                                   const float* __restrict__ y2) {
    int p = blockIdx.x;
    Entry* listm = lists + (size_t)p * CAP;
    const Entry* list = listm;
    int cnt = counts[p]; if (cnt > CAP) cnt = CAP;
    double* acc = accum + (size_t)p * 264;
    float* up = u_g + (size_t)p * NROW;
    float* vp = v_g + (size_t)p * NROW;

    __shared__ float u_s[NROW];   // fallback only
    __shared__ float v_s[NROW];
    __shared__ float redS[2][16];
    __shared__ unsigned redC[16];
    __shared__ int nres_s;
    int t = threadIdx.x;
    int wid = t >> 6, lane = t & 63;

    // ---- folded exact: off-diagonal entries [NROW, cnt) ----
    if (t == 0) nres_s = 0;
    __syncthreads();
    {
        const float* A = (p == 2) ? Y : X;
        const float* B = (p == 0) ? Y : ((p == 1) ? X : Y);
        const float* na = (p == 2) ? y2 : x2;
        const float* nb = (p == 0) ? y2 : ((p == 1) ? x2 : y2);
        int act = 0;
        for (int e = NROW + wid; e < cnt; e += 16) {
            int i = listm[e].i, j = listm[e].j;
            float dot = wave_dot128(A + (size_t)i * DDIM, B + (size_t)j * DDIM, lane);
            if (lane == 0) {
                float raw = na[i] + nb[j] - 2.0f * dot;
                float s, tv; st_from_raw(raw, s, tv);
                listm[e].s = s; listm[e].t = tv;
                if (s != 0.f || tv != 0.f) act++;
            }
        }
        if (lane == 0 && act) atomicAdd(&nres_s, act);
    }
    __syncthreads();
    int nres = nres_s;

    if (nres == 0) {
        float vk[8], uk[8], sk[8];
        unsigned pv2[8];
        #pragma unroll
        for (int k = 0; k < 8; k++) {
            sk[k] = sdiag[p * NROW + t + 1024 * k];
            vk[k] = 1.0f; uk[k] = AC; pv2[k] = 0xFFFFFFFFu;
        }
        unsigned flags = 3u;
        int par = 0, last = 0, done = 0;
        float bu_last = 0.f;
        for (int it = 0; it < NWARM; it++) {
            float s = 0.f;
            #pragma unroll
            for (int k = 0; k < 8; k++) s += vk[k];
            for (int o = 32; o; o >>= 1) s += __shfl_down(s, o, 64);
            if (lane == 0) { redS[par][wid] = s; redC[wid] = flags; }
            __syncthreads();
            float sumv = 0.f; unsigned anyf = 0;
            #pragma unroll
            for (int w2 = 0; w2 < 16; w2++) { sumv += redS[par][w2]; anyf |= redC[w2]; }
            par ^= 1;
            if (it > 0) {
                if (!(anyf & 1)) { done = 1; break; }
                if (!(anyf & 2)) {
                    if (((NITERS - it) & 1) == 0) { done = 1; break; }
                    last = 1;
                }
            }
            float base = 1e-8f * sumv;
            #pragma unroll
            for (int k = 0; k < 8; k++) {
                float kv = fmaxf(base + sk[k] * vk[k], 1e-8f);
                uk[k] = AC * __builtin_amdgcn_rcpf(kv);
            }
            s = 0.f;
            #pragma unroll
            for (int k = 0; k < 8; k++) s += uk[k];
            for (int o = 32; o; o >>= 1) s += __shfl_down(s, o, 64);
            if (lane == 0) redS[par][wid] = s;
            __syncthreads();
            float sumu = 0.f;
            #pragma unroll
            for (int w2 = 0; w2 < 16; w2++) sumu += redS[par][w2];
            par ^= 1;
            base = 1e-8f * sumu;
            bu_last = base;
            unsigned d1 = 0, d2 = 0;
            #pragma unroll
            for (int k = 0; k < 8; k++) {
                float kv = fmaxf(base + sk[k] * uk[k], 1e-8f);
                float nv = AC * __builtin_amdgcn_rcpf(kv);
                unsigned nb_ = __float_as_uint(nv);
                d1 |= nb_ ^ __float_as_uint(vk[k]);
                d2 |= nb_ ^ pv2[k];
                pv2[k] = __float_as_uint(vk[k]);
                vk[k] = nv;
            }
            flags = (__any(d1 != 0) ? 1u : 0u) | (__any(d2 != 0) ? 2u : 0u);
            if (last) { done = 1; break; }
        }
        float bv_f = 0.f;
        int R = 0;
        if (!done) {
            float s = 0.f;
            #pragma unroll
            for (int k = 0; k < 8; k++) s += vk[k];
            for (int o = 32; o; o >>= 1) s += __shfl_down(s, o, 64);
            if (lane == 0) redS[par][wid] = s;
            __syncthreads();
            float sumv = 0.f;
            #pragma unroll
            for (int w2 = 0; w2 < 16; w2++) sumv += redS[par][w2];
            bv_f = 1e-8f * sumv;
            R = NITERS - NWARM;
        }
        #pragma unroll
        for (int k = 0; k < 8; k++) {
            int i = t + 1024 * k;
            up[i] = uk[k]; vp[i] = vk[k];
        }
        if (t == 0) { acc[5] = (double)R; acc[6] = (double)bu_last; acc[7] = (double)bv_f; }
    } else {
        // -------- fallback: general sparse scatter, full 100 iterations --------
        for (int i = t; i < NROW; i += 1024) { u_s[i] = 1.0f; v_s[i] = 1.0f; }
        __syncthreads();
        for (int it = 0; it < NITERS; it++) {
            {
                float sv = 0.f;
                for (int i = t; i < NROW; i += 1024) sv += v_s[i];
                for (int o = 32; o; o >>= 1) sv += __shfl_down(sv, o, 64);
                if (lane == 0) u_s[wid] = sv;
                __syncthreads();
                if (t < 64) {
                    float s2 = (t < 16) ? u_s[t] : 0.f;
                    for (int o = 8; o; o >>= 1) s2 += __shfl_down(s2, o, 64);
                    if (t == 0) u_s[0] = s2;
                }
                __syncthreads();
                float sum_v = u_s[0];
                __syncthreads();
                for (int i = t; i < NROW; i += 1024) u_s[i] = 1e-8f * sum_v;
                __syncthreads();
                for (int e = t; e < cnt; e += 1024)
                    atomicAdd(&u_s[list[e].i], list[e].s * v_s[list[e].j]);
                __syncthreads();
                for (int i = t; i < NROW; i += 1024) u_s[i] = AC / fmaxf(u_s[i], 1e-8f);
                __syncthreads();
            }
            {
                float su = 0.f;
                for (int i = t; i < NROW; i += 1024) su += u_s[i];
                for (int o = 32; o; o >>= 1) su += __shfl_down(su, o, 64);
                if (lane == 0) v_s[wid] = su;
                __syncthreads();
                if (t < 64) {
                    float s2 = (t < 16) ? v_s[t] : 0.f;
                    for (int o = 8; o; o >>= 1) s2 += __shfl_down(s2, o, 64);
                    if (t == 0) v_s[0] = s2;
                }
                __syncthreads();
                float sum_u = v_s[0];
                __syncthreads();
                for (int i = t; i < NROW; i += 1024) v_s[i] = 1e-8f * sum_u;
                __syncthreads();
                for (int e = t; e < cnt; e += 1024)
                    atomicAdd(&v_s[list[e].j], list[e].s * u_s[list[e].i]);
                __syncthreads();
                for (int i = t; i < NROW; i += 1024) v_s[i] = AC / fmaxf(v_s[i], 1e-8f);
                __syncthreads();
            }
        }
        for (int i = t; i < NROW; i += 1024) { up[i] = u_s[i]; vp[i] = v_s[i]; }
        if (t == 0) { acc[5] = 0.0; acc[6] = 0.0; acc[7] = 0.0; }
    }
}

// mega epilogue, 129 blocks/p x 64 rows: per-row frozen-base R iterations +
// Su/Sv/Sux2/Svy2/diag-sp + P,Q (LDS-combined -> 256 atomics/block);
// blockIdx.x==128 does the off-diag sparse correction; LAST finishing block
// (device atomic ctr) runs combine.
__global__ __launch_bounds__(256) void epi_k(const float* __restrict__ X,
                                             const float* __restrict__ Y,
                                             const float* __restrict__ x2,
                                             const float* __restrict__ y2,
                                             const float* __restrict__ sdiag,
                                             const float* __restrict__ tdiag,
                                             const float* __restrict__ u_g,
                                             const float* __restrict__ v_g,
                                             double* accum,
                                             int* counts,
                                             const Entry* __restrict__ lists,
                                             float* __restrict__ out) {
    int p = blockIdx.y;
    double* acc = accum + (size_t)p * 264;
    int t = threadIdx.x, lane = t & 63;
    int R = (int)acc[5];
    float bu = (float)acc[6], bv = (float)acc[7];

    if (blockIdx.x == 128) {
        // off-diag sparse correction; recompute final u_i, v_j per entry
        int cnt = counts[p]; if (cnt > CAP) cnt = CAP;
        const Entry* list = lists + (size_t)p * CAP;
        __shared__ double red[4];
        int wid = t >> 6;
        double sp_ = 0.0;
        for (int e = NROW + t; e < cnt; e += 256) {
            Entry en = list[e];
            if (en.t != 0.f) {
                float si = sdiag[p * NROW + en.i];
                float ui = u_g[p * NROW + en.i], vi = v_g[p * NROW + en.i];
                for (int it2 = 0; it2 < R; it2++) {
                    ui = AC * __builtin_amdgcn_rcpf(fmaxf(bv + si * vi, 1e-8f));
                    vi = AC * __builtin_amdgcn_rcpf(fmaxf(bu + si * ui, 1e-8f));
                }
                float sj = sdiag[p * NROW + en.j];
                float uj = u_g[p * NROW + en.j], vj = v_g[p * NROW + en.j];
                for (int it2 = 0; it2 < R; it2++) {
                    uj = AC * __builtin_amdgcn_rcpf(fmaxf(bv + sj * vj, 1e-8f));
                    vj = AC * __builtin_amdgcn_rcpf(fmaxf(bu + sj * uj, 1e-8f));
                }
                sp_ += (double)ui * (double)vj * (double)en.t;
            }
        }
        for (int o = 32; o; o >>= 1) sp_ += __shfl_down(sp_, o, 64);
        if (lane == 0) red[wid] = sp_;
        __syncthreads();
        if (t == 0) {
            double tot = red[0] + red[1] + red[2] + red[3];
            atomicAdd(&acc[4], tot);
        }
    } else {
        const float* A = (p == 2) ? Y : X;
        const float* B = (p == 0) ? Y : ((p == 1) ? X : Y);
        const float* na = (p == 2) ? y2 : x2;
        const float* nb = (p == 0) ? y2 : ((p == 1) ? x2 : y2);
        int rbase = blockIdx.x * 64;
        __shared__ float us[64], vs[64];
        __shared__ double redP[4][32][4], redQ[4][32][4];   // 8 KB
        if (t < 64) {
            int r = rbase + t;
            // frozen-base iterations for own row (old sinkwide_k)
            float srow = sdiag[p * NROW + r];
            float u = u_g[p * NROW + r], v = v_g[p * NROW + r];
            for (int it2 = 0; it2 < R; it2++) {
                u = AC * __builtin_amdgcn_rcpf(fmaxf(bv + srow * v, 1e-8f));
                v = AC * __builtin_amdgcn_rcpf(fmaxf(bu + srow * u, 1e-8f));
            }
            us[t] = u; vs[t] = v;
            double ui = u, vi = v;
            double a0 = ui, a1 = vi, a2 = ui * (double)na[r], a3 = vi * (double)nb[r];
            double a4 = ui * vi * (double)tdiag[p * NROW + r];
            for (int o = 32; o; o >>= 1) {
                a0 += __shfl_down(a0, o, 64); a1 += __shfl_down(a1, o, 64);
                a2 += __shfl_down(a2, o, 64); a3 += __shfl_down(a3, o, 64);
                a4 += __shfl_down(a4, o, 64);
            }
            if (lane == 0) {
                atomicAdd(&acc[0], a0); atomicAdd(&acc[1], a1);
                atomicAdd(&acc[2], a2); atomicAdd(&acc[3], a3);
                atomicAdd(&acc[4], a4);
            }
        }
        __syncthreads();
        {
            int dq = (t & 31) * 4, g = t >> 5;   // g in [0,8)
            int w = t >> 6;
            double pp[4] = {0, 0, 0, 0}, qq[4] = {0, 0, 0, 0};
            for (int k = 0; k < 8; k++) {
                int rr = g + 8 * k;              // [0,64)
                float4 av = *(const float4*)(A + (size_t)(rbase + rr) * DDIM + dq);
                float usv = us[rr];
                pp[0] += (double)usv * av.x; pp[1] += (double)usv * av.y;
                pp[2] += (double)usv * av.z; pp[3] += (double)usv * av.w;
                float4 bvv = *(const float4*)(B + (size_t)(rbase + rr) * DDIM + dq);
                float vsv = vs[rr];
                qq[0] += (double)vsv * bvv.x; qq[1] += (double)vsv * bvv.y;
                qq[2] += (double)vsv * bvv.z; qq[3] += (double)vsv * bvv.w;
            }
            #pragma unroll
            for (int m = 0; m < 4; m++) {
                pp[m] += __shfl_down(pp[m], 32, 64);
                qq[m] += __shfl_down(qq[m], 32, 64);
            }
            if (lane < 32) {
                #pragma unroll
                for (int m = 0; m < 4; m++) { redP[w][lane][m] = pp[m]; redQ[w][lane][m] = qq[m]; }
            }
            __syncthreads();
            // 256 threads: t<128 -> P[dq..], t>=128 -> Q[dq..]; one atomic each
            int q = t & 127, isQ = t >> 7;
            int dqi = q >> 2, m = q & 3;
            double sum = isQ ? (redQ[0][dqi][m] + redQ[1][dqi][m] + redQ[2][dqi][m] + redQ[3][dqi][m])
                             : (redP[0][dqi][m] + redP[1][dqi][m] + redP[2][dqi][m] + redP[3][dqi][m]);
            atomicAdd(&acc[(isQ ? 136 : 8) + q], sum);
        }
    }

    // ---- last-block combine ----
    __shared__ int lastFlag;
    __syncthreads();
    if (t == 0) {
        __threadfence();
        lastFlag = (atomicAdd(&counts[6], 1) == 386) ? 1 : 0;   // 129*3 blocks
    }
    __syncthreads();
    if (lastFlag) {
        __threadfence();
        __shared__ double costs[3];
        if (t < 64) {
            for (int p2 = 0; p2 < 3; p2++) {
                const double* ac2 = accum + (size_t)p2 * 264;
                double part = ald(ac2 + 8 + t) * ald(ac2 + 136 + t)
                            + ald(ac2 + 8 + 64 + t) * ald(ac2 + 136 + 64 + t);
                for (int o = 32; o; o >>= 1) part += __shfl_down(part, o, 64);
                if (t == 0) {
                    double F = ald(ac2 + 2) * ald(ac2 + 1) + ald(ac2 + 0) * ald(ac2 + 3) - 2.0 * part;
                    double c = 1e-8 * F + ald(ac2 + 4);
                    costs[p2] = (c > 0.0) ? c : 0.0;
                }
            }
        }
        __syncthreads();
        if (t == 0) {
            double dv = costs[0] - 0.5 * (costs[1] + costs[2]);
            dv = fmin(fmax(dv, 0.0), 10000.0);
            out[0] = (float)dv;
        }
    }
}

extern "C" void kernel_launch(void* const* d_in, const int* in_sizes, int n_in,
                              void* d_out, int out_size, void* d_ws, size_t ws_size,
                              hipStream_t stream) {
    const float* X = (const float*)d_in[0];
    const float* Y = (const float*)d_in[1];
    float* out = (float*)d_out;
    char* ws = (char*)d_ws;
    float* x2 = (float*)ws;
    float* y2 = (float*)(ws + 32768);
    float* x2p = (float*)(ws + 65536);
    float* y2p = (float*)(ws + 98304);
    int* counts = (int*)(ws + 131072);
    double* accum = (double*)(ws + 131136);
    Entry* lists = (Entry*)(ws + 137472);
    unsigned short* Xbf = (unsigned short*)(ws + 923904);
    unsigned short* Ybf = (unsigned short*)(ws + 1448192);
    float* sdiag = (float*)(ws + 1972480);
    float* tdiag = (float*)(ws + 2070784);
    float* u_g = (float*)(ws + 2169088);
    float* v_g = (float*)(ws + 2267392);

    norms_k<<<4096, 256, 0, stream>>>(X, Y, x2, y2, x2p, y2p, Xbf, Ybf, counts, accum, lists, sdiag, tdiag);
    scan_k<<<2080, 512, 0, stream>>>(Xbf, Ybf, x2p, y2p, counts, lists);
    sink2_k<<<3, 1024, 0, stream>>>(counts, lists, sdiag, u_g, v_g, accum, X, Y, x2, y2);
    epi_k<<<dim3(129, 3), 256, 0, stream>>>(X, Y, x2, y2, sdiag, tdiag, u_g, v_g, accum, counts, lists, out);
}